// Round 5
// baseline (259.090 us; speedup 1.0000x reference)
//
#include <hip/hip_runtime.h>
#include <cmath>

#define NPTS 262144
#define NLVL 16
#define NDENSE 5
#define HASH_MASK 0x7FFFFu
#define P2 2654435761u
#define P3 805459861u

typedef float v2f __attribute__((ext_vector_type(2)));
typedef float v4f __attribute__((ext_vector_type(4)));

struct MetaU { float scale[NLVL]; unsigned off[NLVL]; unsigned res[NDENSE]; };

struct Pt { float x, y, z; };
struct Prep { unsigned idx[8]; float fx, fy, fz; };

// NT means load: protects XCD-L2-resident tables from the means stream (R1-measured)
__device__ __forceinline__ Pt load_pt_nt(const float* __restrict__ means, int p) {
    Pt q;
    q.x = (__builtin_nontemporal_load(means + 3 * p + 0) + 1.0f) * 0.5f;
    q.y = (__builtin_nontemporal_load(means + 3 * p + 1) + 1.0f) * 0.5f;
    q.z = (__builtin_nontemporal_load(means + 3 * p + 2) + 1.0f) * 0.5f;
    return q;
}

// hash index prep (hsize = 2^19) — off folded into idx; branch-free (R1 exact)
__device__ __forceinline__ Prep hprep(Pt q, float s, unsigned off) {
    const float px = q.x * s, py = q.y * s, pz = q.z * s;
    const float gx = floorf(px), gy = floorf(py), gz = floorf(pz);
    Prep d;
    d.fx = px - gx; d.fy = py - gy; d.fz = pz - gz;
    const unsigned ix = (unsigned)gx, iy = (unsigned)gy, iz = (unsigned)gz;
    const unsigned hy0 = iy * P2, hy1 = hy0 + P2;
    const unsigned hz0 = iz * P3, hz1 = hz0 + P3;
    const unsigned h0 = hy0 ^ hz0, h1 = hy1 ^ hz0, h2 = hy0 ^ hz1, h3 = hy1 ^ hz1;
    d.idx[0] = ((ix ^ h0) & HASH_MASK) + off; d.idx[1] = (((ix + 1u) ^ h0) & HASH_MASK) + off;
    d.idx[2] = ((ix ^ h1) & HASH_MASK) + off; d.idx[3] = (((ix + 1u) ^ h1) & HASH_MASK) + off;
    d.idx[4] = ((ix ^ h2) & HASH_MASK) + off; d.idx[5] = (((ix + 1u) ^ h2) & HASH_MASK) + off;
    d.idx[6] = ((ix ^ h3) & HASH_MASK) + off; d.idx[7] = (((ix + 1u) ^ h3) & HASH_MASK) + off;
    return d;
}

// dense index prep — off folded into idx (R0 exact)
__device__ __forceinline__ Prep dprep(Pt q, float s, unsigned r, unsigned off) {
    const float px = q.x * s, py = q.y * s, pz = q.z * s;
    const float gx = floorf(px), gy = floorf(py), gz = floorf(pz);
    Prep d;
    d.fx = px - gx; d.fy = py - gy; d.fz = pz - gz;
    const unsigned dy = r, dz = r * r;
    const unsigned base = (unsigned)gx + (unsigned)gy * dy + (unsigned)gz * dz + off;
    d.idx[0] = base;           d.idx[1] = base + 1;
    d.idx[2] = base + dy;      d.idx[3] = base + dy + 1;
    d.idx[4] = base + dz;      d.idx[5] = base + dz + 1;
    d.idx[6] = base + dz + dy; d.idx[7] = base + dz + dy + 1;
    return d;
}

__device__ __forceinline__ v2f trilerp(const v2f* f, float fx, float fy, float fz) {
    const float wx0 = 1.0f - fx, wy0 = 1.0f - fy, wz0 = 1.0f - fz;
    const float w00 = wz0 * wy0, w01 = wz0 * fy, w10 = fz * wy0, w11 = fz * fy;
    return w00 * (wx0 * f[0] + fx * f[1]) + w01 * (wx0 * f[2] + fx * f[3])
         + w10 * (wx0 * f[4] + fx * f[5]) + w11 * (wx0 * f[6] + fx * f[7]);
}

// ---------------- ALL 16 levels in one XCD-affine kernel ----------------
// Per-CU gather throughput (~0.44 lanes/cy) is the measured HW ceiling (R1-R4
// invariant); this kernel puts every gather behind that one pipe with no
// serial dense phase. 864 uniform-cost jobs per XCD:
//   slot <  512          : own hash level (5+xcd), 512-pt chunk
//   slot >= 512, xcd < 6, t < 256 : levels 13/14/15 split across XCD pairs
//   else                 : dense big-chunk (1024 pts; ~half cost/pt vs hash)
__global__ __launch_bounds__(256) void encode_all(
    const float* __restrict__ means, const float* __restrict__ emb,
    v2f* __restrict__ dst, int lvl_major, MetaU meta)
{
    const unsigned b = blockIdx.x;
    const unsigned xcd = b & 7u, slot = b >> 3;
    unsigned lvl, base_pt;
    if (slot < 512u) { lvl = 5u + xcd; base_pt = slot * 512u; }
    else {
        const unsigned t = slot - 512u;                      // 0..351
        if (xcd < 6u && t < 256u) {
            lvl = 13u + (xcd >> 1);
            base_pt = (((xcd & 1u) << 8) + t) * 512u;
        } else {
            const unsigned dj = (xcd < 6u) ? (xcd * 96u + (t - 256u))
                                           : (576u + (xcd - 6u) * 352u + t);  // 0..1279
            lvl = dj >> 8;                                   // dense level 0..4
            base_pt = (dj & 255u) * 1024u;
        }
    }
    const float s = meta.scale[lvl];
    const unsigned off = meta.off[lvl];
    const v2f* __restrict__ emb2 = (const v2f*)emb;

    if (lvl < NDENSE) {
        const unsigned r = meta.res[lvl];
        for (unsigned pass = 0; pass < 2u; ++pass) {
            const int p0 = (int)(base_pt + pass * 512u + threadIdx.x);
            const Prep A = dprep(load_pt_nt(means, p0), s, r, off);
            v2f fa[8];
#pragma unroll
            for (int k = 0; k < 8; ++k) fa[k] = emb2[A.idx[k]];
            const Prep B = dprep(load_pt_nt(means, p0 + 256), s, r, off);
            v2f fb[8];
#pragma unroll
            for (int k = 0; k < 8; ++k) fb[k] = emb2[B.idx[k]];

            const v2f ra = trilerp(fa, A.fx, A.fy, A.fz);
            const size_t diA = lvl_major ? ((size_t)lvl * NPTS + p0) : ((size_t)p0 * NLVL + lvl);
            dst[diA] = ra;
            const v2f rb = trilerp(fb, B.fx, B.fy, B.fz);
            const size_t diB = lvl_major ? ((size_t)lvl * NPTS + (p0 + 256)) : ((size_t)(p0 + 256) * NLVL + lvl);
            dst[diB] = rb;
        }
    } else {
        const int p0 = (int)(base_pt + threadIdx.x);
        const Prep A = hprep(load_pt_nt(means, p0), s, off);
        v2f fa[8];
#pragma unroll
        for (int k = 0; k < 8; ++k) fa[k] = emb2[A.idx[k]];
        const Prep B = hprep(load_pt_nt(means, p0 + 256), s, off);
        v2f fb[8];
#pragma unroll
        for (int k = 0; k < 8; ++k) fb[k] = emb2[B.idx[k]];

        const v2f ra = trilerp(fa, A.fx, A.fy, A.fz);
        const size_t diA = lvl_major ? ((size_t)lvl * NPTS + p0) : ((size_t)p0 * NLVL + lvl);
        dst[diA] = ra;
        const v2f rb = trilerp(fb, B.fx, B.fy, B.fz);
        const size_t diB = lvl_major ? ((size_t)lvl * NPTS + (p0 + 256)) : ((size_t)(p0 + 256) * NLVL + lvl);
        dst[diB] = rb;
    }
}

// ---------------- transpose ws[level][point] -> out[point][level] (pure streams) ----------------
__global__ __launch_bounds__(256) void transpose_out(
    const v2f* __restrict__ ws, float* __restrict__ out)
{
    const int p = blockIdx.x * 256 + threadIdx.x;
    v4f o[8];
    v2f* o2 = (v2f*)o;
#pragma unroll
    for (int l = 0; l < NLVL; ++l)
        o2[l] = __builtin_nontemporal_load(&ws[(size_t)l * NPTS + p]);  // single-use
    v4f* out4 = (v4f*)(out + (size_t)p * (2 * NLVL));
#pragma unroll
    for (int k = 0; k < 8; ++k)
        __builtin_nontemporal_store(o[k], &out4[k]);                    // never re-read
}

extern "C" void kernel_launch(void* const* d_in, const int* in_sizes, int n_in,
                              void* d_out, int out_size, void* d_ws, size_t ws_size,
                              hipStream_t stream)
{
    const float* means = (const float*)d_in[0];
    const float* emb   = (const float*)d_in[1];
    float* out         = (float*)d_out;

    MetaU mu;
    const double lg = log2(1.38191288);
    unsigned off = 0;
    for (int l = 0; l < NLVL; ++l) {
        const double scale_d = pow(2.0, (double)l * lg) * 16.0 - 1.0;
        const unsigned res_enc = (unsigned)ceil(scale_d) + 1u;

        const double gres_d = ceil(16.0 * pow(1.38191288, (double)l));
        unsigned long long r3 = (unsigned long long)gres_d;
        r3 = r3 * r3 * r3;
        unsigned long long pl = r3 < (1ull << 19) ? r3 : (1ull << 19);
        pl = (pl + 7ull) / 8ull * 8ull;

        mu.scale[l] = (float)scale_d;
        mu.off[l]   = off;
        if (l < NDENSE) mu.res[l] = res_enc;
        off += (unsigned)pl;
    }

    const size_t ws_needed = (size_t)NLVL * NPTS * sizeof(float) * 2;  // 32 MB
    const bool use_ws = ws_size >= ws_needed;

    if (use_ws) {
        v2f* wsp = (v2f*)d_ws;
        encode_all<<<dim3(8 * 864, 1, 1), 256, 0, stream>>>(means, emb, wsp, 1, mu);
        transpose_out<<<NPTS / 256, 256, 0, stream>>>((const v2f*)wsp, out);
    } else {
        encode_all<<<dim3(8 * 864, 1, 1), 256, 0, stream>>>(means, emb, (v2f*)out, 0, mu);
    }
}

// Round 6
// 210.013 us; speedup vs baseline: 1.2337x; 1.2337x over previous
//
#include <hip/hip_runtime.h>
#include <cmath>

#define NPTS 262144
#define NLVL 16
#define NDENSE 5
#define NHASH 11
#define HASH_MASK 0x7FFFFu
#define P2 2654435761u
#define P3 805459861u

typedef float v2f __attribute__((ext_vector_type(2)));
typedef float v3f __attribute__((ext_vector_type(3)));
typedef float v4f __attribute__((ext_vector_type(4)));
// 16B vector with 8B alignment (dense pair loads are only 8B-aligned)
typedef float v4f8 __attribute__((ext_vector_type(4), aligned(8)));

struct MetaD { float scale[NDENSE]; unsigned off[NDENSE]; unsigned res[NDENSE]; };
struct MetaH { float scale[NHASH]; unsigned off[NHASH]; };

struct Pt { float x, y, z; };
struct Prep { unsigned idx[8]; float fx, fy, fz; };

// ONE dwordx3 address per means read (3 scalar loads cost 3 TA slots; this costs 1).
__device__ __forceinline__ Pt load_pt_nt(const float* __restrict__ means, int p) {
    const v3f m = __builtin_nontemporal_load((const v3f*)(means + 3 * p));
    Pt q;
    q.x = (m.x + 1.0f) * 0.5f;
    q.y = (m.y + 1.0f) * 0.5f;
    q.z = (m.z + 1.0f) * 0.5f;
    return q;
}

// hash index prep (hsize = 2^19) — off folded into idx; branch-free (R1 exact)
__device__ __forceinline__ Prep hprep(Pt q, float s, unsigned off) {
    const float px = q.x * s, py = q.y * s, pz = q.z * s;
    const float gx = floorf(px), gy = floorf(py), gz = floorf(pz);
    Prep d;
    d.fx = px - gx; d.fy = py - gy; d.fz = pz - gz;
    const unsigned ix = (unsigned)gx, iy = (unsigned)gy, iz = (unsigned)gz;
    const unsigned hy0 = iy * P2, hy1 = hy0 + P2;
    const unsigned hz0 = iz * P3, hz1 = hz0 + P3;
    const unsigned h0 = hy0 ^ hz0, h1 = hy1 ^ hz0, h2 = hy0 ^ hz1, h3 = hy1 ^ hz1;
    d.idx[0] = ((ix ^ h0) & HASH_MASK) + off; d.idx[1] = (((ix + 1u) ^ h0) & HASH_MASK) + off;
    d.idx[2] = ((ix ^ h1) & HASH_MASK) + off; d.idx[3] = (((ix + 1u) ^ h1) & HASH_MASK) + off;
    d.idx[4] = ((ix ^ h2) & HASH_MASK) + off; d.idx[5] = (((ix + 1u) ^ h2) & HASH_MASK) + off;
    d.idx[6] = ((ix ^ h3) & HASH_MASK) + off; d.idx[7] = (((ix + 1u) ^ h3) & HASH_MASK) + off;
    return d;
}

__device__ __forceinline__ v2f trilerp(const v2f* f, float fx, float fy, float fz) {
    const float wx0 = 1.0f - fx, wy0 = 1.0f - fy, wz0 = 1.0f - fz;
    const float w00 = wz0 * wy0, w01 = wz0 * fy, w10 = fz * wy0, w11 = fz * fy;
    return w00 * (wx0 * f[0] + fx * f[1]) + w01 * (wx0 * f[2] + fx * f[3])
         + w10 * (wx0 * f[4] + fx * f[5]) + w11 * (wx0 * f[6] + fx * f[7]);
}

// ---------------- hash levels 5..15, XCD-affine, 704 balanced jobs/XCD (R1/R3 mapping) ----------------
__global__ __launch_bounds__(256) void enc_hash(
    const float* __restrict__ means, const float* __restrict__ emb,
    v2f* __restrict__ dst, int lvl_major, MetaH meta)
{
    const unsigned b = blockIdx.x;
    const unsigned xcd = b & 7u, slot = b >> 3;
    unsigned il, chunk;
    if (slot < 512u) { il = xcd; chunk = slot; }
    else {
        const unsigned g = xcd * 192u + (slot - 512u);   // 0..1535 over levels 8..10
        il = 8u + (g >> 9);
        chunk = g & 511u;
    }
    const float s = meta.scale[il];
    const unsigned off = meta.off[il];
    const unsigned lvl = il + NDENSE;
    const int p0 = (int)(chunk * 512u + threadIdx.x);
    const v2f* __restrict__ emb2 = (const v2f*)emb;

    const Prep A = hprep(load_pt_nt(means, p0), s, off);
    v2f fa[8];
#pragma unroll
    for (int k = 0; k < 8; ++k) fa[k] = emb2[A.idx[k]];
    const Prep B = hprep(load_pt_nt(means, p0 + 256), s, off);
    v2f fb[8];
#pragma unroll
    for (int k = 0; k < 8; ++k) fb[k] = emb2[B.idx[k]];

    const v2f ra = trilerp(fa, A.fx, A.fy, A.fz);
    const size_t diA = lvl_major ? ((size_t)lvl * NPTS + p0) : ((size_t)p0 * NLVL + lvl);
    dst[diA] = ra;
    const v2f rb = trilerp(fb, B.fx, B.fy, B.fz);
    const size_t diB = lvl_major ? ((size_t)lvl * NPTS + (p0 + 256)) : ((size_t)(p0 + 256) * NLVL + lvl);
    dst[diB] = rb;
}

// ---------------- fused finalize: dense via pair-quads + ws merge + 128B row write ----------------
// Address budget/point: 11 ws + 1 means + 20 dense-pair + 8 store = 40 (was 62).
__global__ __launch_bounds__(256) void finalize(
    const float* __restrict__ means, const float* __restrict__ emb,
    const v2f* __restrict__ ws, float* __restrict__ out, MetaD meta)
{
    const int p = blockIdx.x * 256 + threadIdx.x;

    // issue the 11 ws reads first (plain: let them hit L2/L3 where encode left them)
    v2f h[NHASH];
#pragma unroll
    for (int l = 0; l < NHASH; ++l)
        h[l] = ws[(size_t)(NDENSE + l) * NPTS + p];

    const Pt q = load_pt_nt(means, p);

    v4f o[8];
    v2f* o2 = (v2f*)o;
#pragma unroll
    for (int l = 0; l < NDENSE; ++l) {
        const float s = meta.scale[l];
        const unsigned off = meta.off[l];
        const unsigned r = meta.res[l];
        const float px = q.x * s, py = q.y * s, pz = q.z * s;
        const float gx = floorf(px), gy = floorf(py), gz = floorf(pz);
        const float fx = px - gx, fy = py - gy, fz = pz - gz;
        const unsigned dy = r, dz = r * r;
        const unsigned base = (unsigned)gx + (unsigned)gy * dy + (unsigned)gz * dz + off;

        // x-pairs are always adjacent in a dense table: 4 pair-quads instead of 8 v2f
        v4f8 F[4];
        F[0] = *(const v4f8*)(emb + 2u * base);
        F[1] = *(const v4f8*)(emb + 2u * (base + dy));
        F[2] = *(const v4f8*)(emb + 2u * (base + dz));
        F[3] = *(const v4f8*)(emb + 2u * (base + dz + dy));

        const float wx0 = 1.0f - fx, wy0 = 1.0f - fy, wz0 = 1.0f - fz;
        const float wc[4] = {wz0 * wy0, wz0 * fy, fz * wy0, fz * fy};
        v2f acc = {0.0f, 0.0f};
#pragma unroll
        for (int c = 0; c < 4; ++c)
            acc += wc[c] * (wx0 * (v2f){F[c].x, F[c].y} + fx * (v2f){F[c].z, F[c].w});
        o2[l] = acc;
    }
#pragma unroll
    for (int l = 0; l < NHASH; ++l)
        o2[NDENSE + l] = h[l];

    v4f* out4 = (v4f*)(out + (size_t)p * (2 * NLVL));
#pragma unroll
    for (int k = 0; k < 8; ++k)
        __builtin_nontemporal_store(o[k], &out4[k]);   // write-only stream
}

// ---------------- fallback dense (point-major direct-to-out), pair-quads ----------------
__global__ __launch_bounds__(256) void enc_dense(
    const float* __restrict__ means, const float* __restrict__ emb,
    v2f* __restrict__ dst, int lvl_major, MetaD meta)
{
    const int p = blockIdx.x * 256 + threadIdx.x;
    const int l = blockIdx.y;

    const Pt q = load_pt_nt(means, p);
    const float s = meta.scale[l];
    const unsigned off = meta.off[l];
    const unsigned r = meta.res[l];

    const float px = q.x * s, py = q.y * s, pz = q.z * s;
    const float gx = floorf(px), gy = floorf(py), gz = floorf(pz);
    const float fx = px - gx, fy = py - gy, fz = pz - gz;
    const unsigned dy = r, dz = r * r;
    const unsigned base = (unsigned)gx + (unsigned)gy * dy + (unsigned)gz * dz + off;

    v4f8 F[4];
    F[0] = *(const v4f8*)(emb + 2u * base);
    F[1] = *(const v4f8*)(emb + 2u * (base + dy));
    F[2] = *(const v4f8*)(emb + 2u * (base + dz));
    F[3] = *(const v4f8*)(emb + 2u * (base + dz + dy));

    const float wx0 = 1.0f - fx, wy0 = 1.0f - fy, wz0 = 1.0f - fz;
    const float wc[4] = {wz0 * wy0, wz0 * fy, fz * wy0, fz * fy};
    v2f acc = {0.0f, 0.0f};
#pragma unroll
    for (int c = 0; c < 4; ++c)
        acc += wc[c] * (wx0 * (v2f){F[c].x, F[c].y} + fx * (v2f){F[c].z, F[c].w});

    const size_t di = lvl_major ? ((size_t)l * NPTS + p) : ((size_t)p * NLVL + l);
    dst[di] = acc;
}

extern "C" void kernel_launch(void* const* d_in, const int* in_sizes, int n_in,
                              void* d_out, int out_size, void* d_ws, size_t ws_size,
                              hipStream_t stream)
{
    const float* means = (const float*)d_in[0];
    const float* emb   = (const float*)d_in[1];
    float* out         = (float*)d_out;

    MetaD md;
    MetaH mh;
    const double lg = log2(1.38191288);
    unsigned off = 0;
    for (int l = 0; l < NLVL; ++l) {
        const double scale_d = pow(2.0, (double)l * lg) * 16.0 - 1.0;
        const unsigned res_enc = (unsigned)ceil(scale_d) + 1u;

        const double gres_d = ceil(16.0 * pow(1.38191288, (double)l));
        unsigned long long r3 = (unsigned long long)gres_d;
        r3 = r3 * r3 * r3;
        unsigned long long pl = r3 < (1ull << 19) ? r3 : (1ull << 19);
        pl = (pl + 7ull) / 8ull * 8ull;

        if (l < NDENSE) {
            md.scale[l] = (float)scale_d;
            md.off[l]   = off;
            md.res[l]   = res_enc;
        } else {
            mh.scale[l - NDENSE] = (float)scale_d;
            mh.off[l - NDENSE]   = off;
        }
        off += (unsigned)pl;
    }

    const size_t ws_needed = (size_t)NLVL * NPTS * sizeof(float) * 2;  // 32 MB
    const bool use_ws = ws_size >= ws_needed;

    if (use_ws) {
        v2f* wsp = (v2f*)d_ws;
        enc_hash<<<dim3(8 * 704, 1, 1), 256, 0, stream>>>(means, emb, wsp, 1, mh);
        finalize<<<NPTS / 256, 256, 0, stream>>>(means, emb, (const v2f*)wsp, out, md);
    } else {
        v2f* dst = (v2f*)out;
        enc_dense<<<dim3(NPTS / 256, NDENSE, 1), 256, 0, stream>>>(means, emb, dst, 0, md);
        enc_hash <<<dim3(8 * 704, 1, 1),          256, 0, stream>>>(means, emb, dst, 0, mh);
    }
}